// Round 4
// baseline (1978.204 us; speedup 1.0000x reference)
//
#include <hip/hip_runtime.h>
#include <math.h>

// DeepSeekMoE: D=5120, F=384, E=32 routed (top-2), S=2 shared, T=1024, fp32.
// Sparse formulation: gate -> per-expert token lists -> grouped fc1+SwiGLU -> grouped fc2 (atomic scatter-add).
// R3: TN 256->128 on both GEMMs (block count 240->480/3200, LDS 83->49KB -> 3 blocks/CU),
//     2-rows-per-global_load_lds weight staging, 8x4 per-thread tile (VALU-bound balance).

#define DD 5120
#define FF 384
#define TWOF 768
#define NE 32
#define TT 1024
#define NG 34          // 32 routed + 2 shared groups
#define CAP 1024       // max tokens per group

#define TM 64          // rows per block tile
#define TK 32

__device__ __forceinline__ void gload_lds16(const float* g, float* l) {
    __builtin_amdgcn_global_load_lds(
        (const __attribute__((address_space(1))) void*)g,
        (__attribute__((address_space(3))) void*)l, 16, 0, 0);
}

__device__ __forceinline__ float sigmoidf_(float v) { return 1.f / (1.f + expf(-v)); }

// ---------------- K1: gating ----------------
__global__ __launch_bounds__(256) void moe_gate(
    const float* __restrict__ x, const float* __restrict__ gate_w,
    const float* __restrict__ gate_b, int* __restrict__ counts,
    int* __restrict__ inst_list, float* __restrict__ wt_list)
{
    int t = blockIdx.x;
    int tid = threadIdx.x;
    int e = tid & 31, chunk = tid >> 5;
    const float* xr = x + (size_t)t * DD;

    float acc = 0.f;
    int k0 = chunk * (DD / 8);
    for (int k = k0; k < k0 + DD / 8; ++k)
        acc = fmaf(xr[k], gate_w[(size_t)k * NE + e], acc);

    __shared__ float part[256];
    part[tid] = acc;
    __syncthreads();

    if (tid < 32) {
        float l = gate_b[e];
        #pragma unroll
        for (int c = 0; c < 8; ++c) l += part[c * 32 + e];

        // softmax over the 32 experts (lanes 0..31 of wave 0)
        float m = l;
        for (int w = 16; w >= 1; w >>= 1) m = fmaxf(m, __shfl_xor(m, w));
        float p = expf(l - m);
        float z = p;
        for (int w = 16; w >= 1; w >>= 1) z += __shfl_xor(z, w);
        float prob = p / z;

        // top-1 (tie -> lower index, matching jax top_k)
        float p1 = prob; int e1 = e;
        for (int w = 16; w >= 1; w >>= 1) {
            float op = __shfl_xor(p1, w); int oe = __shfl_xor(e1, w);
            if (op > p1 || (op == p1 && oe < e1)) { p1 = op; e1 = oe; }
        }
        // top-2
        float pc = (e == e1) ? -1.f : prob;
        float p2 = pc; int e2 = e;
        for (int w = 16; w >= 1; w >>= 1) {
            float op = __shfl_xor(p2, w); int oe = __shfl_xor(e2, w);
            if (op > p2 || (op == p2 && oe < e2)) { p2 = op; e2 = oe; }
        }

        if (tid == 0) {
            int pos1 = atomicAdd(&counts[e1], 1);
            inst_list[e1 * CAP + pos1] = 2 * t;      // instance id: t*2+k
            wt_list[e1 * CAP + pos1] = p1;
            int pos2 = atomicAdd(&counts[e2], 1);
            inst_list[e2 * CAP + pos2] = 2 * t + 1;
            wt_list[e2 * CAP + pos2] = p2;
            // shared pseudo-groups: all tokens, weight 1
            inst_list[32 * CAP + t] = 2048 + t; wt_list[32 * CAP + t] = 1.f;
            inst_list[33 * CAP + t] = 3072 + t; wt_list[33 * CAP + t] = 1.f;
            if (t == 0) { counts[32] = TT; counts[33] = TT; }
        }
    }
}

// ---------------- K2: grouped fc1 + SwiGLU ----------------
// grid: (6 f-tiles of 64, 34 groups, 16 m-tiles of 64). LDS w-tile cols = [64 value | 64 gate].
__global__ __launch_bounds__(256, 3) void moe_fc1(
    const float* __restrict__ x,
    const float* __restrict__ shared_w1, const float* __restrict__ shared_b1,
    const float* __restrict__ routed_w1, const float* __restrict__ routed_b1,
    const int* __restrict__ counts, const int* __restrict__ inst_list,
    float* __restrict__ hidden)
{
    int g = blockIdx.y;
    int ne = counts[g];
    int m0 = blockIdx.z * TM;
    if (m0 >= ne) return;
    int vb = blockIdx.x * 64;   // f offset of this tile

    const float* w1; const float* b1;
    if (g < NE) { w1 = routed_w1 + (size_t)g * DD * TWOF; b1 = routed_b1 + (size_t)g * TWOF; }
    else { int s = g - NE; w1 = shared_w1 + (size_t)s * DD * TWOF; b1 = shared_b1 + (size_t)s * TWOF; }

    __shared__ float xs[2][TK][TM];      // transposed x tile; 2-way write alias = free
    __shared__ float wsm[2][TK][128];    // 512B rows; gload_lds16 covers 2 rows/instr
    __shared__ int sinst[TM];

    int tid = threadIdx.x;
    int nj = tid & 31, mi = tid >> 5;    // compute: 8 rows x (2v+2g)
    int wave = tid >> 6, lane = tid & 63;

    if (tid < TM)
        sinst[tid] = inst_list[g * CAP + min(m0 + tid, ne - 1)];
    __syncthreads();

    // x loader: row = lane, 8 k's per wave
    int kc = wave * 8;
    int linst = sinst[lane];
    int lt = (linst < 2048) ? (linst >> 1) : (linst & (TT - 1));
    const float* xrow = x + (size_t)lt * DD;

    // weight loader: per instr 2 rows; lane 0..31 -> row+0, 32..63 -> row+1
    int lr = lane & 31, rowoff = lane >> 5;
    int gcol = (lr < 16) ? (vb + lr * 4) : (FF + vb + (lr * 4 - 64));

    float accv[8][2] = {};
    float accg[8][2] = {};

    // ---- prologue: stage k=0 into buf 0 ----
    {
        float4 xa = *reinterpret_cast<const float4*>(xrow + kc);
        float4 xb = *reinterpret_cast<const float4*>(xrow + kc + 4);
        xs[0][kc + 0][lane] = xa.x; xs[0][kc + 1][lane] = xa.y;
        xs[0][kc + 2][lane] = xa.z; xs[0][kc + 3][lane] = xa.w;
        xs[0][kc + 4][lane] = xb.x; xs[0][kc + 5][lane] = xb.y;
        xs[0][kc + 6][lane] = xb.z; xs[0][kc + 7][lane] = xb.w;
        #pragma unroll
        for (int i = 0; i < 4; ++i) {
            int row = wave * 8 + i * 2;
            gload_lds16(w1 + (size_t)(row + rowoff) * TWOF + gcol, &wsm[0][row][0]);
        }
    }
    __syncthreads();

    const int NSTEP = DD / TK;   // 160
    int buf = 0;
    for (int t = 0; t < NSTEP; ++t) {
        if (t + 1 < NSTEP) {
            int k0n = (t + 1) * TK;
            int nb = buf ^ 1;
            float4 xa = *reinterpret_cast<const float4*>(xrow + k0n + kc);
            float4 xb = *reinterpret_cast<const float4*>(xrow + k0n + kc + 4);
            xs[nb][kc + 0][lane] = xa.x; xs[nb][kc + 1][lane] = xa.y;
            xs[nb][kc + 2][lane] = xa.z; xs[nb][kc + 3][lane] = xa.w;
            xs[nb][kc + 4][lane] = xb.x; xs[nb][kc + 5][lane] = xb.y;
            xs[nb][kc + 6][lane] = xb.z; xs[nb][kc + 7][lane] = xb.w;
            #pragma unroll
            for (int i = 0; i < 4; ++i) {
                int row = wave * 8 + i * 2;
                gload_lds16(w1 + (size_t)(k0n + row + rowoff) * TWOF + gcol, &wsm[nb][row][0]);
            }
        }
        #pragma unroll
        for (int kk = 0; kk < TK; ++kk) {
            float4 a0 = *reinterpret_cast<const float4*>(&xs[buf][kk][mi * 8]);
            float4 a1 = *reinterpret_cast<const float4*>(&xs[buf][kk][mi * 8 + 4]);
            float2 wv = *reinterpret_cast<const float2*>(&wsm[buf][kk][nj * 2]);
            float2 wg = *reinterpret_cast<const float2*>(&wsm[buf][kk][64 + nj * 2]);
            float ar[8] = {a0.x, a0.y, a0.z, a0.w, a1.x, a1.y, a1.z, a1.w};
            #pragma unroll
            for (int r = 0; r < 8; ++r) {
                accv[r][0] = fmaf(ar[r], wv.x, accv[r][0]);
                accv[r][1] = fmaf(ar[r], wv.y, accv[r][1]);
                accg[r][0] = fmaf(ar[r], wg.x, accg[r][0]);
                accg[r][1] = fmaf(ar[r], wg.y, accg[r][1]);
            }
        }
        __syncthreads();   // drains vmcnt+lgkm; all waves done with buf
        buf ^= 1;
    }

    int f0 = vb + nj * 2;
    float bv0 = b1[f0], bv1 = b1[f0 + 1];
    float bg0 = b1[FF + f0], bg1 = b1[FF + f0 + 1];

    #pragma unroll
    for (int r = 0; r < 8; ++r) {
        int m = m0 + mi * 8 + r;
        if (m < ne) {
            int inst = sinst[mi * 8 + r];
            float v0 = accv[r][0] + bv0, v1 = accv[r][1] + bv1;
            float g0 = accg[r][0] + bg0, g1 = accg[r][1] + bg1;
            float2 o;
            o.x = v0 * sigmoidf_(v0) * g0;
            o.y = v1 * sigmoidf_(v1) * g1;
            *reinterpret_cast<float2*>(&hidden[(size_t)inst * FF + f0]) = o;
        }
    }
}

// ---------------- K3: grouped fc2, scaled scatter-add ----------------
// grid: (40 d-tiles of 128, 34 groups, 16 m-tiles of 64)
__global__ __launch_bounds__(256, 3) void moe_fc2(
    const float* __restrict__ hidden,
    const float* __restrict__ shared_w2, const float* __restrict__ shared_b2,
    const float* __restrict__ routed_w2, const float* __restrict__ routed_b2,
    const int* __restrict__ counts, const int* __restrict__ inst_list,
    const float* __restrict__ wt_list, float* __restrict__ out)
{
    int g = blockIdx.y;
    int ne = counts[g];
    int m0 = blockIdx.z * TM;
    if (m0 >= ne) return;
    int d0 = blockIdx.x * 128;

    const float* w2; const float* b2;
    if (g < NE) { w2 = routed_w2 + (size_t)g * FF * DD; b2 = routed_b2 + (size_t)g * DD; }
    else { int s = g - NE; w2 = shared_w2 + (size_t)s * FF * DD; b2 = shared_b2 + (size_t)s * DD; }

    __shared__ float xs[2][TK][TM];
    __shared__ float wsm[2][TK][128];
    __shared__ int sinst[TM];
    __shared__ float swt[TM];

    int tid = threadIdx.x;
    int nj = tid & 31, mi = tid >> 5;    // compute: 8 rows x 4 d-cols
    int wave = tid >> 6, lane = tid & 63;

    if (tid < TM) {
        int mm = min(m0 + tid, ne - 1);
        sinst[tid] = inst_list[g * CAP + mm];
        swt[tid] = wt_list[g * CAP + mm];
    }
    __syncthreads();

    int kc = wave * 8;
    const float* arow = hidden + (size_t)sinst[lane] * FF;
    int lr = lane & 31, rowoff = lane >> 5;
    int gcol = d0 + lr * 4;

    float acc[8][4] = {};

    // ---- prologue ----
    {
        float4 xa = *reinterpret_cast<const float4*>(arow + kc);
        float4 xb = *reinterpret_cast<const float4*>(arow + kc + 4);
        xs[0][kc + 0][lane] = xa.x; xs[0][kc + 1][lane] = xa.y;
        xs[0][kc + 2][lane] = xa.z; xs[0][kc + 3][lane] = xa.w;
        xs[0][kc + 4][lane] = xb.x; xs[0][kc + 5][lane] = xb.y;
        xs[0][kc + 6][lane] = xb.z; xs[0][kc + 7][lane] = xb.w;
        #pragma unroll
        for (int i = 0; i < 4; ++i) {
            int row = wave * 8 + i * 2;
            gload_lds16(w2 + (size_t)(row + rowoff) * DD + gcol, &wsm[0][row][0]);
        }
    }
    __syncthreads();

    const int NSTEP = FF / TK;   // 12
    int buf = 0;
    for (int t = 0; t < NSTEP; ++t) {
        if (t + 1 < NSTEP) {
            int k0n = (t + 1) * TK;
            int nb = buf ^ 1;
            float4 xa = *reinterpret_cast<const float4*>(arow + k0n + kc);
            float4 xb = *reinterpret_cast<const float4*>(arow + k0n + kc + 4);
            xs[nb][kc + 0][lane] = xa.x; xs[nb][kc + 1][lane] = xa.y;
            xs[nb][kc + 2][lane] = xa.z; xs[nb][kc + 3][lane] = xa.w;
            xs[nb][kc + 4][lane] = xb.x; xs[nb][kc + 5][lane] = xb.y;
            xs[nb][kc + 6][lane] = xb.z; xs[nb][kc + 7][lane] = xb.w;
            #pragma unroll
            for (int i = 0; i < 4; ++i) {
                int row = wave * 8 + i * 2;
                gload_lds16(w2 + (size_t)(k0n + row + rowoff) * DD + gcol, &wsm[nb][row][0]);
            }
        }
        #pragma unroll
        for (int kk = 0; kk < TK; ++kk) {
            float4 a0 = *reinterpret_cast<const float4*>(&xs[buf][kk][mi * 8]);
            float4 a1 = *reinterpret_cast<const float4*>(&xs[buf][kk][mi * 8 + 4]);
            float4 wl = *reinterpret_cast<const float4*>(&wsm[buf][kk][nj * 4]);
            float ar[8] = {a0.x, a0.y, a0.z, a0.w, a1.x, a1.y, a1.z, a1.w};
            #pragma unroll
            for (int r = 0; r < 8; ++r) {
                acc[r][0] = fmaf(ar[r], wl.x, acc[r][0]);
                acc[r][1] = fmaf(ar[r], wl.y, acc[r][1]);
                acc[r][2] = fmaf(ar[r], wl.z, acc[r][2]);
                acc[r][3] = fmaf(ar[r], wl.w, acc[r][3]);
            }
        }
        __syncthreads();
        buf ^= 1;
    }

    float b2v[4];
    #pragma unroll
    for (int c = 0; c < 4; ++c) b2v[c] = b2[d0 + nj * 4 + c];

    #pragma unroll
    for (int r = 0; r < 8; ++r) {
        int m = m0 + mi * 8 + r;
        if (m < ne) {
            int inst = sinst[mi * 8 + r];
            int t = (inst < 2048) ? (inst >> 1) : (inst & (TT - 1));
            float p = swt[mi * 8 + r];
            float* orow = out + (size_t)t * DD + d0 + nj * 4;
            #pragma unroll
            for (int c = 0; c < 4; ++c)
                atomicAdd(&orow[c], p * (acc[r][c] + b2v[c]));
        }
    }
}

// ---------------- launch ----------------
extern "C" void kernel_launch(void* const* d_in, const int* in_sizes, int n_in,
                              void* d_out, int out_size, void* d_ws, size_t ws_size,
                              hipStream_t stream)
{
    const float* x          = (const float*)d_in[0];
    const float* gate_w     = (const float*)d_in[1];
    const float* gate_b     = (const float*)d_in[2];
    const float* shared_w1  = (const float*)d_in[3];
    const float* shared_b1  = (const float*)d_in[4];
    const float* shared_w2  = (const float*)d_in[5];
    const float* shared_b2  = (const float*)d_in[6];
    const float* routed_w1  = (const float*)d_in[7];
    const float* routed_b1  = (const float*)d_in[8];
    const float* routed_w2  = (const float*)d_in[9];
    const float* routed_b2  = (const float*)d_in[10];
    float* out = (float*)d_out;

    // ws layout (total ~6.6 MB): counts[64] | inst[34*1024] | wt[34*1024] | hidden[4096*384]
    int*   counts    = (int*)d_ws;
    int*   inst_list = counts + 64;
    float* wt_list   = (float*)(inst_list + NG * CAP);
    float* hidden    = wt_list + NG * CAP;

    hipMemsetAsync(counts, 0, 64 * sizeof(int), stream);
    hipMemsetAsync(out, 0, (size_t)TT * DD * sizeof(float), stream);

    moe_gate<<<dim3(TT), dim3(256), 0, stream>>>(x, gate_w, gate_b, counts, inst_list, wt_list);
    moe_fc1<<<dim3(6, NG, TT / TM), dim3(256), 0, stream>>>(
        x, shared_w1, shared_b1, routed_w1, routed_b1, counts, inst_list, hidden);
    moe_fc2<<<dim3(40, NG, TT / TM), dim3(256), 0, stream>>>(
        hidden, shared_w2, shared_b2, routed_w2, routed_b2, counts, inst_list, wt_list, out);
}